// Round 14
// baseline (101.970 us; speedup 1.0000x reference)
//
#include <hip/hip_runtime.h>
#include <hip/hip_bf16.h>

#define B_ 8
#define N_ 2048
#define C_ 32
#define S_ 32
#define O1_ 128
#define NP_ (B_*N_)          // 16384 points
#define MTOTF 524288.0f      // B*N*S samples per BN channel
#define NCOPY 64             // stat partial copies (R13: 8 -> R14: 64)

typedef __attribute__((ext_vector_type(8))) short s16x8;
typedef __attribute__((ext_vector_type(4))) float f32x4;
typedef __attribute__((ext_vector_type(2))) int   i32x2;

__device__ __forceinline__ short bfr(float x){
    return __builtin_bit_cast(short, __float2bfloat16(x));
}
__device__ __forceinline__ float lrelu(float x){ return fmaxf(x, 0.2f*x); }

// ================= k_pre: ssum + point transpose + w0 tables + w1->bf16 ====
// H0r[gi,o] = sum_c w0[o,32+c]*x[c] ; base[gi,o] = sum_c (w0[o,c]-w0[o,32+c])*x[c]
// (b0/b1 dropped: BatchNorm cancels additive per-channel constants exactly)
__global__ __launch_bounds__(256) void k_pre(const float* __restrict__ pf,
        const float* __restrict__ w0, const float* __restrict__ w1,
        float* __restrict__ H0r, float* __restrict__ base,
        float* __restrict__ pt, double* __restrict__ ssum,
        unsigned short* __restrict__ w1b){
    __shared__ float w0t[32*65], w0d[32*65];   // transposed, pitch 65
    const int t = threadIdx.x, w = t >> 6, l = t & 63;
    for (int i = t; i < 2048; i += 256){
        int o = i >> 5, c = i & 31;
        float a = w0[o*64 + c], bq = w0[o*64 + 32 + c];
        w0t[c*65 + o] = bq;
        w0d[c*65 + o] = a - bq;
    }
    if (blockIdx.x == 0){
        // w1 -> bf16, XOR-swizzled in global so k_main can linear-copy to LDS
        for (int i = t; i < 8192; i += 256){
            int o = i >> 6, k = i & 63;
            w1b[(o << 6) | (k ^ ((o & 7) << 3))] = (unsigned short)bfr(w1[i]);
        }
    }
    __syncthreads();
    for (int gi = blockIdx.x*4 + w; gi < NP_; gi += 4096){
        int b = gi >> 11;
        int n = gi & (N_-1);
        const float* pp = pf + (size_t)b*C_*N_ + n;
        float hacc = 0.f, dacc = 0.f, xv = 0.f;
        double s = 0.0;
        #pragma unroll
        for (int c = 0; c < 32; ++c){
            float xc = pp[(size_t)c*N_];          // wave-uniform broadcast load
            hacc = fmaf(w0t[c*65 + l], xc, hacc);
            dacc = fmaf(w0d[c*65 + l], xc, dacc);
            double xd = (double)xc;
            s = fma(xd, xd, s);
            if (l == c) xv = xc;
        }
        H0r[(size_t)gi*64 + l]  = hacc;
        base[(size_t)gi*64 + l] = dacc;
        if (l < 32) pt[(size_t)gi*32 + l] = xv;
        if (l == 0) ssum[gi] = s;
    }
}

// ================= k_knn: ball query (f32) + fused BN0 stats ===============
// batch-pinned: blockIdx&7 = batch -> per-XCD L2 holds one batch's tables
// R14 = R13 body with partial-copy count 8 -> 64 (blockIdx&63): per-address
// atomic RMW chain 128 -> 16. R13 (8 copies) proved the contention theory:
// total 123.9 -> 96.8us. This tests whether residual contention remains.
__global__ __launch_bounds__(256,2) void k_knn(const float* __restrict__ pt,
        const double* __restrict__ ssum, const float* __restrict__ H0r,
        const float* __restrict__ base, int* __restrict__ idxb,
        float* __restrict__ gstat0p){
    __shared__ int sidx[4][S_];
    __shared__ float r1[4][64], r2[4][64];
    const int t = threadIdx.x, w = t >> 6, lane = t & 63;
    const int b = blockIdx.x & 7, chunk = blockIdx.x >> 3;   // 128 chunks/batch
    const int gp0 = b*N_ + chunk*16 + w*4;                   // 4 points per wave
    const float* ptb = pt + (size_t)(b*N_)*32;
    const double* ssb = ssum + (size_t)b*N_;
    const float* hb = H0r + (size_t)(b*N_)*64 + lane;
    const unsigned long long below = (1ull << lane) - 1ull;
    const float4* r0p = (const float4*)(ptb + (size_t)lane*32);
    const float4* r1p = (const float4*)(ptb + (size_t)(64+lane)*32);
    float4 va[8], vb[8];
    #pragma unroll
    for (int j = 0; j < 8; ++j) va[j] = r0p[j];
    #pragma unroll
    for (int j = 0; j < 8; ++j) vb[j] = r1p[j];
    bool valid = true;
    const float ss0 = (float)ssb[lane], ss1 = (float)ssb[64+lane];
    float asum = 0.f, asq = 0.f;
    #pragma unroll 1
    for (int pp = 0; pp < 4; ++pp){
        const int gi = gp0 + pp;
        if (!valid){   // rare: a previous tail run clobbered va/vb
            #pragma unroll
            for (int j = 0; j < 8; ++j) va[j] = r0p[j];
            #pragma unroll
            for (int j = 0; j < 8; ++j) vb[j] = r1p[j];
            valid = true;
        }
        float cn[32];
        {
            const float* cp = pt + (size_t)gi*32;
            #pragma unroll
            for (int j = 0; j < 8; ++j){
                float4 v = ((const float4*)cp)[j];
                cn[4*j]   = v.x; cn[4*j+1] = v.y;
                cn[4*j+2] = v.z; cn[4*j+3] = v.w;
            }
        }
        const float sn = (float)ssum[gi];
        int cnt;
        {   // rows 0..127 from persistent registers, all-f32 FMA chain
            float d0 = 0.f, d1 = 0.f;
            #pragma unroll
            for (int j = 0; j < 8; ++j){
                d0 = fmaf(va[j].x, cn[4*j],   d0);
                d0 = fmaf(va[j].y, cn[4*j+1], d0);
                d0 = fmaf(va[j].z, cn[4*j+2], d0);
                d0 = fmaf(va[j].w, cn[4*j+3], d0);
                d1 = fmaf(vb[j].x, cn[4*j],   d1);
                d1 = fmaf(vb[j].y, cn[4*j+1], d1);
                d1 = fmaf(vb[j].z, cn[4*j+2], d1);
                d1 = fmaf(vb[j].w, cn[4*j+3], d1);
            }
            float sq0 = sn + ss0 - 2.0f*d0;
            float sq1 = sn + ss1 - 2.0f*d1;
            bool q0 = !(sq0 > 64.0f), q1 = !(sq1 > 64.0f);
            unsigned long long m0 = __ballot(q0), m1 = __ballot(q1);
            int p0 = __popcll(m0);
            int rk0 = __popcll(m0 & below);
            int rk1 = p0 + __popcll(m1 & below);
            if (q0 && rk0 < S_) sidx[w][rk0] = lane;
            if (q1 && rk1 < S_) sidx[w][rk1] = 64 + lane;
            cnt = p0 + __popcll(m1);
        }
        if (cnt < S_){   // rare tail: 2 tiles per iteration, clobbers va/vb
            #pragma unroll 1
            for (int mb = 128; mb < N_ && cnt < S_; mb += 128){
                const int ma = mb + lane, mc = mb + 64 + lane;
                const float4* ta = (const float4*)(ptb + (size_t)ma*32);
                const float4* tb = (const float4*)(ptb + (size_t)mc*32);
                #pragma unroll
                for (int j = 0; j < 8; ++j) va[j] = ta[j];
                #pragma unroll
                for (int j = 0; j < 8; ++j) vb[j] = tb[j];
                float d0 = 0.f, d1 = 0.f;
                #pragma unroll
                for (int j = 0; j < 8; ++j){
                    d0 = fmaf(va[j].x, cn[4*j],   d0);
                    d0 = fmaf(va[j].y, cn[4*j+1], d0);
                    d0 = fmaf(va[j].z, cn[4*j+2], d0);
                    d0 = fmaf(va[j].w, cn[4*j+3], d0);
                    d1 = fmaf(vb[j].x, cn[4*j],   d1);
                    d1 = fmaf(vb[j].y, cn[4*j+1], d1);
                    d1 = fmaf(vb[j].z, cn[4*j+2], d1);
                    d1 = fmaf(vb[j].w, cn[4*j+3], d1);
                }
                float sq0 = sn + (float)ssb[ma] - 2.0f*d0;
                float sq1 = sn + (float)ssb[mc] - 2.0f*d1;
                bool q0 = !(sq0 > 64.0f), q1 = !(sq1 > 64.0f);
                unsigned long long m0 = __ballot(q0), m1 = __ballot(q1);
                int c0 = __popcll(m0);
                int rk0 = cnt + __popcll(m0 & below);
                int rk1 = cnt + c0 + __popcll(m1 & below);
                if (q0 && rk0 < S_) sidx[w][rk0] = ma;
                if (q1 && rk1 < S_) sidx[w][rk1] = mc;
                cnt += c0 + __popcll(m1);
            }
            valid = false;
        }
        int first = sidx[w][0];
        int myi = first;
        if (lane < S_){
            myi = (lane < cnt) ? sidx[w][lane] : first;
            idxb[gi*S_ + lane] = myi;
        }
        // fused BN0 stats: lane = channel
        float bse = base[(size_t)gi*64 + lane];
        #pragma unroll 16
        for (int s = 0; s < S_; ++s){
            int ms = __shfl(myi, s);
            float h = bse + hb[(size_t)ms*64];
            asum += h; asq = fmaf(h, h, asq);
        }
    }
    r1[w][lane] = asum; r2[w][lane] = asq;
    __syncthreads();
    {   // partial copy (blockIdx&63): 16 RMWs per address instead of 128
        float* gp = gstat0p + (size_t)(blockIdx.x & (NCOPY-1))*128;
        if (t < 64){
            atomicAdd(&gp[t], r1[0][t]+r1[1][t]+r1[2][t]+r1[3][t]);
        } else if (t < 128){
            int o = t - 64;
            atomicAdd(&gp[64+o], r2[0][o]+r2[1][o]+r2[2][o]+r2[3][o]);
        }
    }
}

// ================= k_main: fused bn0 + bf16 MFMA layer1 + BN1 stats + sel-max
// (256,3): ~150-reg working set fits 170-VGPR budget; (256,4) caused ~100MB
// of spill stores (R3) with occupancy scratch-capped below the 3-wave bound.
// DO NOT raise to (256,4): combined arch+accum regs > 128 (R3 evidence).
__global__ __launch_bounds__(256,3) void k_main(
        const float* __restrict__ H0r, const float* __restrict__ base,
        const int* __restrict__ idxb, const unsigned short* __restrict__ w1b,
        const float* __restrict__ g0, const float* __restrict__ be0,
        const float* __restrict__ g1,
        const float* __restrict__ gstat0p, float* __restrict__ gstat1p,
        float* __restrict__ selb){
    __shared__ unsigned short w1s[8192];     // 16KB, XOR-swizzled bf16 w1
    __shared__ float bn0s[128];
    __shared__ float baseS[16*64];           // 4KB: base rows of block's points
    __shared__ int   idxS[16*S_];            // 2KB: idx rows of block's points
    __shared__ float sred[4][O1_], qred[4][O1_];
    const int t = threadIdx.x, w = t >> 6, l = t & 63;
    const int lr = l & 15, g = l >> 4;
    const int b = blockIdx.x & 7, chunk = blockIdx.x >> 3;
    const int rowb = b*N_;
    const int p0g = rowb + chunk*16;         // first point of this block
    {   // stage w1 (already swizzled in global) -> LDS, linear copy
        const s16x8* src = (const s16x8*)w1b;
        s16x8* dst = (s16x8*)w1s;
        #pragma unroll
        for (int j = 0; j < 4; ++j) dst[t + 256*j] = src[t + 256*j];
        // stage base rows (16*64 f32) and idx rows (16*32 i32), coalesced, NT
        ((f32x4*)baseS)[t] = __builtin_nontemporal_load(
            (const f32x4*)(base + (size_t)p0g*64) + t);
        ((i32x2*)idxS)[t] = __builtin_nontemporal_load(
            (const i32x2*)(idxb + (size_t)p0g*S_) + t);
    }
    if (t < 64){   // fused bn0: sum the 64 partial copies, then scale/shift
        float s0 = 0.f, s1 = 0.f;
        #pragma unroll 8
        for (int k = 0; k < NCOPY; ++k){
            s0 += gstat0p[k*128 + t];
            s1 += gstat0p[k*128 + 64 + t];
        }
        float mean = s0 * (1.f/MTOTF);
        float var  = s1 * (1.f/MTOTF) - mean*mean;
        float sc = g0[t] * rsqrtf(var + 1e-5f);
        bn0s[t] = sc; bn0s[64+t] = be0[t] - mean*sc;
    }
    __syncthreads();
    // sign of g1 decides max vs min (min = -max(-x)); packed to 1 register
    unsigned smask = 0u;
    #pragma unroll
    for (int nt = 0; nt < 8; ++nt)
        if (g1[nt*16+lr] < 0.f) smask |= (1u << nt);
    const char* wbp = (const char*)w1s;
    int bo0v = lr*128 + ((g*16) ^ ((lr & 7) << 4));
    int bo1v = bo0v ^ 64;
    float bsum[8] = {0,0,0,0,0,0,0,0};
    float bsqr[8] = {0,0,0,0,0,0,0,0};
    float gaf[32];
    auto ISSUE = [&](int i0_, int i1_){
        const float* h0 = H0r + (size_t)(rowb + i0_)*64 + g*8;
        const float* h1 = H0r + (size_t)(rowb + i1_)*64 + g*8;
        *(float4*)&gaf[0]  = ((const float4*)h0)[0];
        *(float4*)&gaf[4]  = ((const float4*)h0)[1];
        *(float4*)&gaf[8]  = *(const float4*)(h0+32);
        *(float4*)&gaf[12] = *(const float4*)(h0+36);
        *(float4*)&gaf[16] = ((const float4*)h1)[0];
        *(float4*)&gaf[20] = ((const float4*)h1)[1];
        *(float4*)&gaf[24] = *(const float4*)(h1+32);
        *(float4*)&gaf[28] = *(const float4*)(h1+36);
    };
    {
        int ci0 = idxS[(w*4)*S_ + lr];
        int ci1 = idxS[(w*4)*S_ + 16 + lr];
        ISSUE(ci0, ci1);
    }
    #pragma unroll 1
    for (int p = 0; p < 4; ++p){
        // opaque touch: compiler must treat w1 LDS offsets as loop-variant,
        // so the 16 ds_read_b128 of w1 cannot be hoisted (64 VGPRs saved)
        asm volatile("" : "+v"(bo0v), "+v"(bo1v));
        const int cgi = p0g + w*4 + p;
        const float* bls = &baseS[(w*4+p)*64];
        // bn0 scale/shift (LDS broadcast), base folded into shift, per-kt half
        s16x8 Af[2][2];
        #pragma unroll
        for (int kt = 0; kt < 2; ++kt){
            float scv[8], shft[8];
            #pragma unroll
            for (int j = 0; j < 8; ++j){
                float sc = bn0s[kt*32 + g*8 + j];
                float sh = bn0s[64 + kt*32 + g*8 + j];
                scv[j] = sc;
                shft[j] = fmaf(sc, bls[kt*32 + g*8 + j], sh);
            }
            #pragma unroll
            for (int mt = 0; mt < 2; ++mt){
                s16x8 f;
                #pragma unroll
                for (int j = 0; j < 8; ++j){
                    float v = fmaf(scv[j], gaf[mt*16+kt*8+j], shft[j]);
                    v = fmaxf(v, 0.2f*v);
                    f[j] = bfr(v);
                }
                Af[mt][kt] = f;
            }
        }
        if (p < 3){   // prefetch next point's H rows under the MFMA loop
            int ni0 = idxS[(w*4+p+1)*S_ + lr];
            int ni1 = idxS[(w*4+p+1)*S_ + 16 + lr];
            ISSUE(ni0, ni1);
        }
        #pragma unroll
        for (int nt = 0; nt < 8; ++nt){
            s16x8 b0 = *(const s16x8*)(wbp + bo0v + nt*2048);
            s16x8 b1 = *(const s16x8*)(wbp + bo1v + nt*2048);
            f32x4 ac0 = {0.f,0.f,0.f,0.f}, ac1 = {0.f,0.f,0.f,0.f};
            ac0 = __builtin_amdgcn_mfma_f32_16x16x32_bf16(Af[0][0], b0, ac0, 0,0,0);
            ac0 = __builtin_amdgcn_mfma_f32_16x16x32_bf16(Af[0][1], b1, ac0, 0,0,0);
            ac1 = __builtin_amdgcn_mfma_f32_16x16x32_bf16(Af[1][0], b0, ac1, 0,0,0);
            ac1 = __builtin_amdgcn_mfma_f32_16x16x32_bf16(Af[1][1], b1, ac1, 0,0,0);
            float v0=ac0[0],v1=ac0[1],v2=ac0[2],v3=ac0[3];
            float v4=ac1[0],v5=ac1[1],v6=ac1[2],v7=ac1[3];
            bsum[nt] += ((v0+v1)+(v2+v3)) + ((v4+v5)+(v6+v7));
            float q = bsqr[nt];
            q = fmaf(v0,v0,q); q = fmaf(v1,v1,q); q = fmaf(v2,v2,q); q = fmaf(v3,v3,q);
            q = fmaf(v4,v4,q); q = fmaf(v5,v5,q); q = fmaf(v6,v6,q); q = fmaf(v7,v7,q);
            bsqr[nt] = q;
            const unsigned s = ((smask >> nt) & 1u) << 31;
            float x0 = __uint_as_float(__float_as_uint(v0)^s);
            float x1 = __uint_as_float(__float_as_uint(v1)^s);
            float x2 = __uint_as_float(__float_as_uint(v2)^s);
            float x3 = __uint_as_float(__float_as_uint(v3)^s);
            float x4 = __uint_as_float(__float_as_uint(v4)^s);
            float x5 = __uint_as_float(__float_as_uint(v5)^s);
            float x6 = __uint_as_float(__float_as_uint(v6)^s);
            float x7 = __uint_as_float(__float_as_uint(v7)^s);
            float mm = fmaxf(fmaxf(fmaxf(x0,x1), fmaxf(x2,x3)),
                             fmaxf(fmaxf(x4,x5), fmaxf(x6,x7)));
            mm = fmaxf(mm, __shfl_xor(mm, 16));
            mm = fmaxf(mm, __shfl_xor(mm, 32));
            if (l < 16)
                __builtin_nontemporal_store(
                    __uint_as_float(__float_as_uint(mm)^s),
                    &selb[(size_t)cgi*O1_ + nt*16 + lr]);
        }
    }
    // BN1-stat reduction: wave -> block -> partial-copy atomics
    #pragma unroll
    for (int nt = 0; nt < 8; ++nt){
        float s = bsum[nt]; s += __shfl_xor(s, 16); s += __shfl_xor(s, 32);
        float q = bsqr[nt]; q += __shfl_xor(q, 16); q += __shfl_xor(q, 32);
        if (l < 16){ sred[w][nt*16 + lr] = s; qred[w][nt*16 + lr] = q; }
    }
    __syncthreads();
    {
        float* gp = gstat1p + (size_t)(blockIdx.x & (NCOPY-1))*256;
        if (t < O1_){
            atomicAdd(&gp[t], sred[0][t]+sred[1][t]+sred[2][t]+sred[3][t]);
        } else {
            int o = t - O1_;
            atomicAdd(&gp[O1_+o], qred[0][o]+qred[1][o]+qred[2][o]+qred[3][o]);
        }
    }
}

// ================= k_out: fused bn1 + lrelu + transpose ====================
__global__ __launch_bounds__(256) void k_out(const float* __restrict__ selb,
        const float* __restrict__ gstat1p, const float* __restrict__ g1,
        const float* __restrict__ be1, float* __restrict__ out){
    __shared__ float bn1s[256];
    __shared__ float tr[O1_][65];
    const int t = threadIdx.x;
    if (t < O1_){   // sum the 64 partial copies, then scale/shift
        float s0 = 0.f, s1 = 0.f;
        #pragma unroll 8
        for (int k = 0; k < NCOPY; ++k){
            s0 += gstat1p[k*256 + t];
            s1 += gstat1p[k*256 + O1_ + t];
        }
        float mean = s0 * (1.f/MTOTF);
        float var  = s1 * (1.f/MTOTF) - mean*mean;
        float sc = g1[t] * rsqrtf(var + 1e-5f);
        bn1s[t] = sc; bn1s[O1_+t] = be1[t] - mean*sc;
    }
    __syncthreads();
    const int b  = blockIdx.x >> 5;
    const int n0 = (blockIdx.x & 31) * 64;
    #pragma unroll
    for (int it = 0; it < 32; ++it){
        int e = t + 256*it;
        int O = e & 127, nl = e >> 7;
        float v = selb[(size_t)(b*N_ + n0 + nl)*O1_ + O];
        tr[O][nl] = lrelu(bn1s[O]*v + bn1s[O1_+O]);
    }
    __syncthreads();
    #pragma unroll
    for (int it = 0; it < 32; ++it){
        int e = t + 256*it;
        int nl = e & 63, O = e >> 6;
        out[((size_t)(b*O1_) + O)*N_ + n0 + nl] = tr[O][nl];
    }
}

extern "C" void kernel_launch(void* const* d_in, const int* in_sizes, int n_in,
                              void* d_out, int out_size, void* d_ws, size_t ws_size,
                              hipStream_t stream){
    const float* pf  = (const float*)d_in[1];
    const float* w0  = (const float*)d_in[2];
    const float* g0  = (const float*)d_in[4];
    const float* be0 = (const float*)d_in[5];
    const float* w1  = (const float*)d_in[6];
    const float* g1  = (const float*)d_in[8];
    const float* be1 = (const float*)d_in[9];
    float* out = (float*)d_out;

    char* ws = (char*)d_ws;
    size_t off = 0;
    auto carve = [&](size_t bytes)->void*{
        void* p = ws + off; off += (bytes + 255) & ~(size_t)255; return p;
    };
    double* ssum  = (double*)carve((size_t)NP_*8);
    int*    idxb  = (int*)   carve((size_t)NP_*S_*4);
    float*  H0r   = (float*) carve((size_t)NP_*64*4);
    float*  base  = (float*) carve((size_t)NP_*64*4);
    float*  pt    = (float*) carve((size_t)NP_*32*4);
    unsigned short* w1b = (unsigned short*)carve(8192*2);
    float*  gstats = (float*)carve((size_t)NCOPY*384*4);  // 64x128 + 64x256
    float*  selb  = (float*) carve((size_t)NP_*O1_*4);
    float* gstat0p = gstats;                 // 64 copies x 128 floats
    float* gstat1p = gstats + NCOPY*128;     // 64 copies x 256 floats

    hipMemsetAsync(gstats, 0, (size_t)NCOPY*384*4, stream);
    k_pre <<<1024, 256, 0, stream>>>(pf, w0, w1, H0r, base, pt, ssum, w1b);
    k_knn <<<1024, 256, 0, stream>>>(pt, ssum, H0r, base, idxb, gstat0p);
    k_main<<<1024, 256, 0, stream>>>(H0r, base, idxb, w1b, g0, be0, g1,
                                     gstat0p, gstat1p, selb);
    k_out <<<256, 256, 0, stream>>>(selb, gstat1p, g1, be1, out);
}

// Round 15
// 93.773 us; speedup vs baseline: 1.0874x; 1.0874x over previous
//
#include <hip/hip_runtime.h>
#include <hip/hip_bf16.h>

#define B_ 8
#define N_ 2048
#define C_ 32
#define S_ 32
#define O1_ 128
#define NP_ (B_*N_)          // 16384 points
#define MTOTF 524288.0f      // B*N*S samples per BN channel
#define NCOPY 8              // stat partial copies (R13 proven; R14's 64 = null)

typedef __attribute__((ext_vector_type(8))) short s16x8;
typedef __attribute__((ext_vector_type(4))) float f32x4;
typedef __attribute__((ext_vector_type(2))) int   i32x2;

__device__ __forceinline__ short bfr(float x){
    return __builtin_bit_cast(short, __float2bfloat16(x));
}
__device__ __forceinline__ float lrelu(float x){ return fmaxf(x, 0.2f*x); }

// ================= k_pre: ssum + point transpose + w0 tables + w1->bf16 ====
// H0r[gi,o] = sum_c w0[o,32+c]*x[c] ; base[gi,o] = sum_c (w0[o,c]-w0[o,32+c])*x[c]
// R15: batch-pinned block mapping (blockIdx&7 = batch), IDENTICAL to k_knn/
// k_main. Previously k_pre wrote batch b's tables from blocks on all 8 XCDs
// while k_knn always reads batch b on XCD b -> cross-XCD L2 misses at L3
// latency (~3x L2) on every table read. Producing on the consuming XCD keeps
// batch b's ~1.4MB working set in XCD b's 4MB L2. Same math, same outputs.
__global__ __launch_bounds__(256) void k_pre(const float* __restrict__ pf,
        const float* __restrict__ w0, const float* __restrict__ w1,
        float* __restrict__ H0r, float* __restrict__ base,
        float* __restrict__ pt, double* __restrict__ ssum,
        unsigned short* __restrict__ w1b){
    __shared__ float w0t[32*65], w0d[32*65];   // transposed, pitch 65
    const int t = threadIdx.x, w = t >> 6, l = t & 63;
    for (int i = t; i < 2048; i += 256){
        int o = i >> 5, c = i & 31;
        float a = w0[o*64 + c], bq = w0[o*64 + 32 + c];
        w0t[c*65 + o] = bq;
        w0d[c*65 + o] = a - bq;
    }
    if (blockIdx.x == 0){
        // w1 -> bf16, XOR-swizzled in global so k_main can linear-copy to LDS
        for (int i = t; i < 8192; i += 256){
            int o = i >> 6, k = i & 63;
            w1b[(o << 6) | (k ^ ((o & 7) << 3))] = (unsigned short)bfr(w1[i]);
        }
    }
    __syncthreads();
    const int b = blockIdx.x & 7, chunk = blockIdx.x >> 3;   // 128 chunks/batch
    const int gp0 = b*N_ + chunk*16 + w*4;                   // 4 points per wave
    const float* pfb = pf + (size_t)b*C_*N_;
    #pragma unroll 1
    for (int pp = 0; pp < 4; ++pp){
        const int gi = gp0 + pp;
        const int n = gi & (N_-1);
        const float* ppx = pfb + n;
        float hacc = 0.f, dacc = 0.f, xv = 0.f;
        double s = 0.0;
        #pragma unroll
        for (int c = 0; c < 32; ++c){
            float xc = ppx[(size_t)c*N_];         // wave-uniform broadcast load
            hacc = fmaf(w0t[c*65 + l], xc, hacc);
            dacc = fmaf(w0d[c*65 + l], xc, dacc);
            double xd = (double)xc;
            s = fma(xd, xd, s);
            if (l == c) xv = xc;
        }
        H0r[(size_t)gi*64 + l]  = hacc;
        base[(size_t)gi*64 + l] = dacc;
        if (l < 32) pt[(size_t)gi*32 + l] = xv;
        if (l == 0) ssum[gi] = s;
    }
}

// ================= k_knn: ball query (f32) + fused BN0 stats ===============
// batch-pinned: blockIdx&7 = batch -> per-XCD L2 holds one batch's tables
// Body = R9/R13 proven form (f32, VGPR 68, (256,2)); per-XCD stat partials.
__global__ __launch_bounds__(256,2) void k_knn(const float* __restrict__ pt,
        const double* __restrict__ ssum, const float* __restrict__ H0r,
        const float* __restrict__ base, int* __restrict__ idxb,
        float* __restrict__ gstat0p){
    __shared__ int sidx[4][S_];
    __shared__ float r1[4][64], r2[4][64];
    const int t = threadIdx.x, w = t >> 6, lane = t & 63;
    const int b = blockIdx.x & 7, chunk = blockIdx.x >> 3;   // 128 chunks/batch
    const int gp0 = b*N_ + chunk*16 + w*4;                   // 4 points per wave
    const float* ptb = pt + (size_t)(b*N_)*32;
    const double* ssb = ssum + (size_t)b*N_;
    const float* hb = H0r + (size_t)(b*N_)*64 + lane;
    const unsigned long long below = (1ull << lane) - 1ull;
    const float4* r0p = (const float4*)(ptb + (size_t)lane*32);
    const float4* r1p = (const float4*)(ptb + (size_t)(64+lane)*32);
    float4 va[8], vb[8];
    #pragma unroll
    for (int j = 0; j < 8; ++j) va[j] = r0p[j];
    #pragma unroll
    for (int j = 0; j < 8; ++j) vb[j] = r1p[j];
    bool valid = true;
    const float ss0 = (float)ssb[lane], ss1 = (float)ssb[64+lane];
    float asum = 0.f, asq = 0.f;
    #pragma unroll 1
    for (int pp = 0; pp < 4; ++pp){
        const int gi = gp0 + pp;
        if (!valid){   // rare: a previous tail run clobbered va/vb
            #pragma unroll
            for (int j = 0; j < 8; ++j) va[j] = r0p[j];
            #pragma unroll
            for (int j = 0; j < 8; ++j) vb[j] = r1p[j];
            valid = true;
        }
        float cn[32];
        {
            const float* cp = pt + (size_t)gi*32;
            #pragma unroll
            for (int j = 0; j < 8; ++j){
                float4 v = ((const float4*)cp)[j];
                cn[4*j]   = v.x; cn[4*j+1] = v.y;
                cn[4*j+2] = v.z; cn[4*j+3] = v.w;
            }
        }
        const float sn = (float)ssum[gi];
        int cnt;
        {   // rows 0..127 from persistent registers, all-f32 FMA chain
            float d0 = 0.f, d1 = 0.f;
            #pragma unroll
            for (int j = 0; j < 8; ++j){
                d0 = fmaf(va[j].x, cn[4*j],   d0);
                d0 = fmaf(va[j].y, cn[4*j+1], d0);
                d0 = fmaf(va[j].z, cn[4*j+2], d0);
                d0 = fmaf(va[j].w, cn[4*j+3], d0);
                d1 = fmaf(vb[j].x, cn[4*j],   d1);
                d1 = fmaf(vb[j].y, cn[4*j+1], d1);
                d1 = fmaf(vb[j].z, cn[4*j+2], d1);
                d1 = fmaf(vb[j].w, cn[4*j+3], d1);
            }
            float sq0 = sn + ss0 - 2.0f*d0;
            float sq1 = sn + ss1 - 2.0f*d1;
            bool q0 = !(sq0 > 64.0f), q1 = !(sq1 > 64.0f);
            unsigned long long m0 = __ballot(q0), m1 = __ballot(q1);
            int p0 = __popcll(m0);
            int rk0 = __popcll(m0 & below);
            int rk1 = p0 + __popcll(m1 & below);
            if (q0 && rk0 < S_) sidx[w][rk0] = lane;
            if (q1 && rk1 < S_) sidx[w][rk1] = 64 + lane;
            cnt = p0 + __popcll(m1);
        }
        if (cnt < S_){   // rare tail: 2 tiles per iteration, clobbers va/vb
            #pragma unroll 1
            for (int mb = 128; mb < N_ && cnt < S_; mb += 128){
                const int ma = mb + lane, mc = mb + 64 + lane;
                const float4* ta = (const float4*)(ptb + (size_t)ma*32);
                const float4* tb = (const float4*)(ptb + (size_t)mc*32);
                #pragma unroll
                for (int j = 0; j < 8; ++j) va[j] = ta[j];
                #pragma unroll
                for (int j = 0; j < 8; ++j) vb[j] = tb[j];
                float d0 = 0.f, d1 = 0.f;
                #pragma unroll
                for (int j = 0; j < 8; ++j){
                    d0 = fmaf(va[j].x, cn[4*j],   d0);
                    d0 = fmaf(va[j].y, cn[4*j+1], d0);
                    d0 = fmaf(va[j].z, cn[4*j+2], d0);
                    d0 = fmaf(va[j].w, cn[4*j+3], d0);
                    d1 = fmaf(vb[j].x, cn[4*j],   d1);
                    d1 = fmaf(vb[j].y, cn[4*j+1], d1);
                    d1 = fmaf(vb[j].z, cn[4*j+2], d1);
                    d1 = fmaf(vb[j].w, cn[4*j+3], d1);
                }
                float sq0 = sn + (float)ssb[ma] - 2.0f*d0;
                float sq1 = sn + (float)ssb[mc] - 2.0f*d1;
                bool q0 = !(sq0 > 64.0f), q1 = !(sq1 > 64.0f);
                unsigned long long m0 = __ballot(q0), m1 = __ballot(q1);
                int c0 = __popcll(m0);
                int rk0 = cnt + __popcll(m0 & below);
                int rk1 = cnt + c0 + __popcll(m1 & below);
                if (q0 && rk0 < S_) sidx[w][rk0] = ma;
                if (q1 && rk1 < S_) sidx[w][rk1] = mc;
                cnt += c0 + __popcll(m1);
            }
            valid = false;
        }
        int first = sidx[w][0];
        int myi = first;
        if (lane < S_){
            myi = (lane < cnt) ? sidx[w][lane] : first;
            idxb[gi*S_ + lane] = myi;
        }
        // fused BN0 stats: lane = channel
        float bse = base[(size_t)gi*64 + lane];
        #pragma unroll 16
        for (int s = 0; s < S_; ++s){
            int ms = __shfl(myi, s);
            float h = bse + hb[(size_t)ms*64];
            asum += h; asq = fmaf(h, h, asq);
        }
    }
    r1[w][lane] = asum; r2[w][lane] = asq;
    __syncthreads();
    {   // per-XCD partial: copy (blockIdx&7); contention/8, no XCD ping-pong
        float* gp = gstat0p + (size_t)(blockIdx.x & (NCOPY-1))*128;
        if (t < 64){
            atomicAdd(&gp[t], r1[0][t]+r1[1][t]+r1[2][t]+r1[3][t]);
        } else if (t < 128){
            int o = t - 64;
            atomicAdd(&gp[64+o], r2[0][o]+r2[1][o]+r2[2][o]+r2[3][o]);
        }
    }
}

// ================= k_main: fused bn0 + bf16 MFMA layer1 + BN1 stats + sel-max
// (256,3): ~150-reg working set fits 170-VGPR budget; (256,4) caused ~100MB
// of spill stores (R3) with occupancy scratch-capped below the 3-wave bound.
// DO NOT raise to (256,4): combined arch+accum regs > 128 (R3 evidence).
__global__ __launch_bounds__(256,3) void k_main(
        const float* __restrict__ H0r, const float* __restrict__ base,
        const int* __restrict__ idxb, const unsigned short* __restrict__ w1b,
        const float* __restrict__ g0, const float* __restrict__ be0,
        const float* __restrict__ g1,
        const float* __restrict__ gstat0p, float* __restrict__ gstat1p,
        float* __restrict__ selb){
    __shared__ unsigned short w1s[8192];     // 16KB, XOR-swizzled bf16 w1
    __shared__ float bn0s[128];
    __shared__ float baseS[16*64];           // 4KB: base rows of block's points
    __shared__ int   idxS[16*S_];            // 2KB: idx rows of block's points
    __shared__ float sred[4][O1_], qred[4][O1_];
    const int t = threadIdx.x, w = t >> 6, l = t & 63;
    const int lr = l & 15, g = l >> 4;
    const int b = blockIdx.x & 7, chunk = blockIdx.x >> 3;
    const int rowb = b*N_;
    const int p0g = rowb + chunk*16;         // first point of this block
    {   // stage w1 (already swizzled in global) -> LDS, linear copy
        const s16x8* src = (const s16x8*)w1b;
        s16x8* dst = (s16x8*)w1s;
        #pragma unroll
        for (int j = 0; j < 4; ++j) dst[t + 256*j] = src[t + 256*j];
        // stage base rows (16*64 f32) and idx rows (16*32 i32), coalesced, NT
        ((f32x4*)baseS)[t] = __builtin_nontemporal_load(
            (const f32x4*)(base + (size_t)p0g*64) + t);
        ((i32x2*)idxS)[t] = __builtin_nontemporal_load(
            (const i32x2*)(idxb + (size_t)p0g*S_) + t);
    }
    if (t < 64){   // fused bn0: sum the 8 per-XCD partials, then scale/shift
        float s0 = 0.f, s1 = 0.f;
        #pragma unroll
        for (int k = 0; k < NCOPY; ++k){
            s0 += gstat0p[k*128 + t];
            s1 += gstat0p[k*128 + 64 + t];
        }
        float mean = s0 * (1.f/MTOTF);
        float var  = s1 * (1.f/MTOTF) - mean*mean;
        float sc = g0[t] * rsqrtf(var + 1e-5f);
        bn0s[t] = sc; bn0s[64+t] = be0[t] - mean*sc;
    }
    __syncthreads();
    // sign of g1 decides max vs min (min = -max(-x)); packed to 1 register
    unsigned smask = 0u;
    #pragma unroll
    for (int nt = 0; nt < 8; ++nt)
        if (g1[nt*16+lr] < 0.f) smask |= (1u << nt);
    const char* wbp = (const char*)w1s;
    int bo0v = lr*128 + ((g*16) ^ ((lr & 7) << 4));
    int bo1v = bo0v ^ 64;
    float bsum[8] = {0,0,0,0,0,0,0,0};
    float bsqr[8] = {0,0,0,0,0,0,0,0};
    float gaf[32];
    auto ISSUE = [&](int i0_, int i1_){
        const float* h0 = H0r + (size_t)(rowb + i0_)*64 + g*8;
        const float* h1 = H0r + (size_t)(rowb + i1_)*64 + g*8;
        *(float4*)&gaf[0]  = ((const float4*)h0)[0];
        *(float4*)&gaf[4]  = ((const float4*)h0)[1];
        *(float4*)&gaf[8]  = *(const float4*)(h0+32);
        *(float4*)&gaf[12] = *(const float4*)(h0+36);
        *(float4*)&gaf[16] = ((const float4*)h1)[0];
        *(float4*)&gaf[20] = ((const float4*)h1)[1];
        *(float4*)&gaf[24] = *(const float4*)(h1+32);
        *(float4*)&gaf[28] = *(const float4*)(h1+36);
    };
    {
        int ci0 = idxS[(w*4)*S_ + lr];
        int ci1 = idxS[(w*4)*S_ + 16 + lr];
        ISSUE(ci0, ci1);
    }
    #pragma unroll 1
    for (int p = 0; p < 4; ++p){
        // opaque touch: compiler must treat w1 LDS offsets as loop-variant,
        // so the 16 ds_read_b128 of w1 cannot be hoisted (64 VGPRs saved)
        asm volatile("" : "+v"(bo0v), "+v"(bo1v));
        const int cgi = p0g + w*4 + p;
        const float* bls = &baseS[(w*4+p)*64];
        // bn0 scale/shift (LDS broadcast), base folded into shift, per-kt half
        s16x8 Af[2][2];
        #pragma unroll
        for (int kt = 0; kt < 2; ++kt){
            float scv[8], shft[8];
            #pragma unroll
            for (int j = 0; j < 8; ++j){
                float sc = bn0s[kt*32 + g*8 + j];
                float sh = bn0s[64 + kt*32 + g*8 + j];
                scv[j] = sc;
                shft[j] = fmaf(sc, bls[kt*32 + g*8 + j], sh);
            }
            #pragma unroll
            for (int mt = 0; mt < 2; ++mt){
                s16x8 f;
                #pragma unroll
                for (int j = 0; j < 8; ++j){
                    float v = fmaf(scv[j], gaf[mt*16+kt*8+j], shft[j]);
                    v = fmaxf(v, 0.2f*v);
                    f[j] = bfr(v);
                }
                Af[mt][kt] = f;
            }
        }
        if (p < 3){   // prefetch next point's H rows under the MFMA loop
            int ni0 = idxS[(w*4+p+1)*S_ + lr];
            int ni1 = idxS[(w*4+p+1)*S_ + 16 + lr];
            ISSUE(ni0, ni1);
        }
        #pragma unroll
        for (int nt = 0; nt < 8; ++nt){
            s16x8 b0 = *(const s16x8*)(wbp + bo0v + nt*2048);
            s16x8 b1 = *(const s16x8*)(wbp + bo1v + nt*2048);
            f32x4 ac0 = {0.f,0.f,0.f,0.f}, ac1 = {0.f,0.f,0.f,0.f};
            ac0 = __builtin_amdgcn_mfma_f32_16x16x32_bf16(Af[0][0], b0, ac0, 0,0,0);
            ac0 = __builtin_amdgcn_mfma_f32_16x16x32_bf16(Af[0][1], b1, ac0, 0,0,0);
            ac1 = __builtin_amdgcn_mfma_f32_16x16x32_bf16(Af[1][0], b0, ac1, 0,0,0);
            ac1 = __builtin_amdgcn_mfma_f32_16x16x32_bf16(Af[1][1], b1, ac1, 0,0,0);
            float v0=ac0[0],v1=ac0[1],v2=ac0[2],v3=ac0[3];
            float v4=ac1[0],v5=ac1[1],v6=ac1[2],v7=ac1[3];
            bsum[nt] += ((v0+v1)+(v2+v3)) + ((v4+v5)+(v6+v7));
            float q = bsqr[nt];
            q = fmaf(v0,v0,q); q = fmaf(v1,v1,q); q = fmaf(v2,v2,q); q = fmaf(v3,v3,q);
            q = fmaf(v4,v4,q); q = fmaf(v5,v5,q); q = fmaf(v6,v6,q); q = fmaf(v7,v7,q);
            bsqr[nt] = q;
            const unsigned s = ((smask >> nt) & 1u) << 31;
            float x0 = __uint_as_float(__float_as_uint(v0)^s);
            float x1 = __uint_as_float(__float_as_uint(v1)^s);
            float x2 = __uint_as_float(__float_as_uint(v2)^s);
            float x3 = __uint_as_float(__float_as_uint(v3)^s);
            float x4 = __uint_as_float(__float_as_uint(v4)^s);
            float x5 = __uint_as_float(__float_as_uint(v5)^s);
            float x6 = __uint_as_float(__float_as_uint(v6)^s);
            float x7 = __uint_as_float(__float_as_uint(v7)^s);
            float mm = fmaxf(fmaxf(fmaxf(x0,x1), fmaxf(x2,x3)),
                             fmaxf(fmaxf(x4,x5), fmaxf(x6,x7)));
            mm = fmaxf(mm, __shfl_xor(mm, 16));
            mm = fmaxf(mm, __shfl_xor(mm, 32));
            if (l < 16)
                __builtin_nontemporal_store(
                    __uint_as_float(__float_as_uint(mm)^s),
                    &selb[(size_t)cgi*O1_ + nt*16 + lr]);
        }
    }
    // BN1-stat reduction: wave -> block -> per-XCD partial atomics
    #pragma unroll
    for (int nt = 0; nt < 8; ++nt){
        float s = bsum[nt]; s += __shfl_xor(s, 16); s += __shfl_xor(s, 32);
        float q = bsqr[nt]; q += __shfl_xor(q, 16); q += __shfl_xor(q, 32);
        if (l < 16){ sred[w][nt*16 + lr] = s; qred[w][nt*16 + lr] = q; }
    }
    __syncthreads();
    {
        float* gp = gstat1p + (size_t)(blockIdx.x & (NCOPY-1))*256;
        if (t < O1_){
            atomicAdd(&gp[t], sred[0][t]+sred[1][t]+sred[2][t]+sred[3][t]);
        } else {
            int o = t - O1_;
            atomicAdd(&gp[O1_+o], qred[0][o]+qred[1][o]+qred[2][o]+qred[3][o]);
        }
    }
}

// ================= k_out: fused bn1 + lrelu + transpose ====================
__global__ __launch_bounds__(256) void k_out(const float* __restrict__ selb,
        const float* __restrict__ gstat1p, const float* __restrict__ g1,
        const float* __restrict__ be1, float* __restrict__ out){
    __shared__ float bn1s[256];
    __shared__ float tr[O1_][65];
    const int t = threadIdx.x;
    if (t < O1_){   // sum the 8 per-XCD partials, then scale/shift
        float s0 = 0.f, s1 = 0.f;
        #pragma unroll
        for (int k = 0; k < NCOPY; ++k){
            s0 += gstat1p[k*256 + t];
            s1 += gstat1p[k*256 + O1_ + t];
        }
        float mean = s0 * (1.f/MTOTF);
        float var  = s1 * (1.f/MTOTF) - mean*mean;
        float sc = g1[t] * rsqrtf(var + 1e-5f);
        bn1s[t] = sc; bn1s[O1_+t] = be1[t] - mean*sc;
    }
    __syncthreads();
    const int b  = blockIdx.x >> 5;
    const int n0 = (blockIdx.x & 31) * 64;
    #pragma unroll
    for (int it = 0; it < 32; ++it){
        int e = t + 256*it;
        int O = e & 127, nl = e >> 7;
        float v = selb[(size_t)(b*N_ + n0 + nl)*O1_ + O];
        tr[O][nl] = lrelu(bn1s[O]*v + bn1s[O1_+O]);
    }
    __syncthreads();
    #pragma unroll
    for (int it = 0; it < 32; ++it){
        int e = t + 256*it;
        int nl = e & 63, O = e >> 6;
        out[((size_t)(b*O1_) + O)*N_ + n0 + nl] = tr[O][nl];
    }
}

extern "C" void kernel_launch(void* const* d_in, const int* in_sizes, int n_in,
                              void* d_out, int out_size, void* d_ws, size_t ws_size,
                              hipStream_t stream){
    const float* pf  = (const float*)d_in[1];
    const float* w0  = (const float*)d_in[2];
    const float* g0  = (const float*)d_in[4];
    const float* be0 = (const float*)d_in[5];
    const float* w1  = (const float*)d_in[6];
    const float* g1  = (const float*)d_in[8];
    const float* be1 = (const float*)d_in[9];
    float* out = (float*)d_out;

    char* ws = (char*)d_ws;
    size_t off = 0;
    auto carve = [&](size_t bytes)->void*{
        void* p = ws + off; off += (bytes + 255) & ~(size_t)255; return p;
    };
    double* ssum  = (double*)carve((size_t)NP_*8);
    int*    idxb  = (int*)   carve((size_t)NP_*S_*4);
    float*  H0r   = (float*) carve((size_t)NP_*64*4);
    float*  base  = (float*) carve((size_t)NP_*64*4);
    float*  pt    = (float*) carve((size_t)NP_*32*4);
    unsigned short* w1b = (unsigned short*)carve(8192*2);
    float*  gstats = (float*)carve((size_t)NCOPY*384*4);  // 8x128 + 8x256
    float*  selb  = (float*) carve((size_t)NP_*O1_*4);
    float* gstat0p = gstats;                 // 8 copies x 128 floats
    float* gstat1p = gstats + NCOPY*128;     // 8 copies x 256 floats

    hipMemsetAsync(gstats, 0, (size_t)NCOPY*384*4, stream);
    k_pre <<<1024, 256, 0, stream>>>(pf, w0, w1, H0r, base, pt, ssum, w1b);
    k_knn <<<1024, 256, 0, stream>>>(pt, ssum, H0r, base, idxb, gstat0p);
    k_main<<<1024, 256, 0, stream>>>(H0r, base, idxb, w1b, g0, be0, g1,
                                     gstat0p, gstat1p, selb);
    k_out <<<256, 256, 0, stream>>>(selb, gstat1p, g1, be1, out);
}

// Round 16
// 89.189 us; speedup vs baseline: 1.1433x; 1.0514x over previous
//
#include <hip/hip_runtime.h>
#include <hip/hip_bf16.h>

#define B_ 8
#define N_ 2048
#define C_ 32
#define S_ 32
#define O1_ 128
#define NP_ (B_*N_)          // 16384 points
#define MTOTF 524288.0f      // B*N*S samples per BN channel
#define NCOPY 8              // stat partial copies (R13 proven; R14's 64 = null)

typedef __attribute__((ext_vector_type(8))) short s16x8;
typedef __attribute__((ext_vector_type(4))) float f32x4;
typedef __attribute__((ext_vector_type(2))) int   i32x2;

__device__ __forceinline__ short bfr(float x){
    return __builtin_bit_cast(short, __float2bfloat16(x));
}
__device__ __forceinline__ float lrelu(float x){ return fmaxf(x, 0.2f*x); }

// ================= k_pre: ssum + point transpose + w0 tables + w1->bf16 ====
// H0r[gi,o] = sum_c w0[o,32+c]*x[c] ; base[gi,o] = sum_c (w0[o,c]-w0[o,32+c])*x[c]
// R15: batch-pinned block mapping (blockIdx&7 = batch) = k_knn/k_main mapping
// (produce on the consuming XCD). R16: block 0 also zeroes the 12KB gstats
// buffer, replacing the hipMemsetAsync whose fill dispatch profiled at 43us.
__global__ __launch_bounds__(256) void k_pre(const float* __restrict__ pf,
        const float* __restrict__ w0, const float* __restrict__ w1,
        float* __restrict__ H0r, float* __restrict__ base,
        float* __restrict__ pt, double* __restrict__ ssum,
        unsigned short* __restrict__ w1b, float* __restrict__ gstats){
    __shared__ float w0t[32*65], w0d[32*65];   // transposed, pitch 65
    const int t = threadIdx.x, w = t >> 6, l = t & 63;
    for (int i = t; i < 2048; i += 256){
        int o = i >> 5, c = i & 31;
        float a = w0[o*64 + c], bq = w0[o*64 + 32 + c];
        w0t[c*65 + o] = bq;
        w0d[c*65 + o] = a - bq;
    }
    if (blockIdx.x == 0){
        // w1 -> bf16, XOR-swizzled in global so k_main can linear-copy to LDS
        for (int i = t; i < 8192; i += 256){
            int o = i >> 6, k = i & 63;
            w1b[(o << 6) | (k ^ ((o & 7) << 3))] = (unsigned short)bfr(w1[i]);
        }
        // zero the stat partials (replaces hipMemsetAsync fill dispatch):
        // kernel completion guarantees visibility to k_knn/k_main
        #pragma unroll
        for (int i = 0; i < 3; ++i)
            ((f32x4*)gstats)[t + 256*i] = (f32x4){0.f,0.f,0.f,0.f};
    }
    __syncthreads();
    const int b = blockIdx.x & 7, chunk = blockIdx.x >> 3;   // 128 chunks/batch
    const int gp0 = b*N_ + chunk*16 + w*4;                   // 4 points per wave
    const float* pfb = pf + (size_t)b*C_*N_;
    #pragma unroll 1
    for (int pp = 0; pp < 4; ++pp){
        const int gi = gp0 + pp;
        const int n = gi & (N_-1);
        const float* ppx = pfb + n;
        float hacc = 0.f, dacc = 0.f, xv = 0.f;
        double s = 0.0;
        #pragma unroll
        for (int c = 0; c < 32; ++c){
            float xc = ppx[(size_t)c*N_];         // wave-uniform broadcast load
            hacc = fmaf(w0t[c*65 + l], xc, hacc);
            dacc = fmaf(w0d[c*65 + l], xc, dacc);
            double xd = (double)xc;
            s = fma(xd, xd, s);
            if (l == c) xv = xc;
        }
        H0r[(size_t)gi*64 + l]  = hacc;
        base[(size_t)gi*64 + l] = dacc;
        if (l < 32) pt[(size_t)gi*32 + l] = xv;
        if (l == 0) ssum[gi] = s;
    }
}

// ================= k_knn: ball query (f32) + fused BN0 stats ===============
// batch-pinned: blockIdx&7 = batch -> per-XCD L2 holds one batch's tables
// Body = R9/R13 proven form (f32, VGPR 68, (256,2)); per-XCD stat partials.
__global__ __launch_bounds__(256,2) void k_knn(const float* __restrict__ pt,
        const double* __restrict__ ssum, const float* __restrict__ H0r,
        const float* __restrict__ base, int* __restrict__ idxb,
        float* __restrict__ gstat0p){
    __shared__ int sidx[4][S_];
    __shared__ float r1[4][64], r2[4][64];
    const int t = threadIdx.x, w = t >> 6, lane = t & 63;
    const int b = blockIdx.x & 7, chunk = blockIdx.x >> 3;   // 128 chunks/batch
    const int gp0 = b*N_ + chunk*16 + w*4;                   // 4 points per wave
    const float* ptb = pt + (size_t)(b*N_)*32;
    const double* ssb = ssum + (size_t)b*N_;
    const float* hb = H0r + (size_t)(b*N_)*64 + lane;
    const unsigned long long below = (1ull << lane) - 1ull;
    const float4* r0p = (const float4*)(ptb + (size_t)lane*32);
    const float4* r1p = (const float4*)(ptb + (size_t)(64+lane)*32);
    float4 va[8], vb[8];
    #pragma unroll
    for (int j = 0; j < 8; ++j) va[j] = r0p[j];
    #pragma unroll
    for (int j = 0; j < 8; ++j) vb[j] = r1p[j];
    bool valid = true;
    const float ss0 = (float)ssb[lane], ss1 = (float)ssb[64+lane];
    float asum = 0.f, asq = 0.f;
    #pragma unroll 1
    for (int pp = 0; pp < 4; ++pp){
        const int gi = gp0 + pp;
        if (!valid){   // rare: a previous tail run clobbered va/vb
            #pragma unroll
            for (int j = 0; j < 8; ++j) va[j] = r0p[j];
            #pragma unroll
            for (int j = 0; j < 8; ++j) vb[j] = r1p[j];
            valid = true;
        }
        float cn[32];
        {
            const float* cp = pt + (size_t)gi*32;
            #pragma unroll
            for (int j = 0; j < 8; ++j){
                float4 v = ((const float4*)cp)[j];
                cn[4*j]   = v.x; cn[4*j+1] = v.y;
                cn[4*j+2] = v.z; cn[4*j+3] = v.w;
            }
        }
        const float sn = (float)ssum[gi];
        int cnt;
        {   // rows 0..127 from persistent registers, all-f32 FMA chain
            float d0 = 0.f, d1 = 0.f;
            #pragma unroll
            for (int j = 0; j < 8; ++j){
                d0 = fmaf(va[j].x, cn[4*j],   d0);
                d0 = fmaf(va[j].y, cn[4*j+1], d0);
                d0 = fmaf(va[j].z, cn[4*j+2], d0);
                d0 = fmaf(va[j].w, cn[4*j+3], d0);
                d1 = fmaf(vb[j].x, cn[4*j],   d1);
                d1 = fmaf(vb[j].y, cn[4*j+1], d1);
                d1 = fmaf(vb[j].z, cn[4*j+2], d1);
                d1 = fmaf(vb[j].w, cn[4*j+3], d1);
            }
            float sq0 = sn + ss0 - 2.0f*d0;
            float sq1 = sn + ss1 - 2.0f*d1;
            bool q0 = !(sq0 > 64.0f), q1 = !(sq1 > 64.0f);
            unsigned long long m0 = __ballot(q0), m1 = __ballot(q1);
            int p0 = __popcll(m0);
            int rk0 = __popcll(m0 & below);
            int rk1 = p0 + __popcll(m1 & below);
            if (q0 && rk0 < S_) sidx[w][rk0] = lane;
            if (q1 && rk1 < S_) sidx[w][rk1] = 64 + lane;
            cnt = p0 + __popcll(m1);
        }
        if (cnt < S_){   // rare tail: 2 tiles per iteration, clobbers va/vb
            #pragma unroll 1
            for (int mb = 128; mb < N_ && cnt < S_; mb += 128){
                const int ma = mb + lane, mc = mb + 64 + lane;
                const float4* ta = (const float4*)(ptb + (size_t)ma*32);
                const float4* tb = (const float4*)(ptb + (size_t)mc*32);
                #pragma unroll
                for (int j = 0; j < 8; ++j) va[j] = ta[j];
                #pragma unroll
                for (int j = 0; j < 8; ++j) vb[j] = tb[j];
                float d0 = 0.f, d1 = 0.f;
                #pragma unroll
                for (int j = 0; j < 8; ++j){
                    d0 = fmaf(va[j].x, cn[4*j],   d0);
                    d0 = fmaf(va[j].y, cn[4*j+1], d0);
                    d0 = fmaf(va[j].z, cn[4*j+2], d0);
                    d0 = fmaf(va[j].w, cn[4*j+3], d0);
                    d1 = fmaf(vb[j].x, cn[4*j],   d1);
                    d1 = fmaf(vb[j].y, cn[4*j+1], d1);
                    d1 = fmaf(vb[j].z, cn[4*j+2], d1);
                    d1 = fmaf(vb[j].w, cn[4*j+3], d1);
                }
                float sq0 = sn + (float)ssb[ma] - 2.0f*d0;
                float sq1 = sn + (float)ssb[mc] - 2.0f*d1;
                bool q0 = !(sq0 > 64.0f), q1 = !(sq1 > 64.0f);
                unsigned long long m0 = __ballot(q0), m1 = __ballot(q1);
                int c0 = __popcll(m0);
                int rk0 = cnt + __popcll(m0 & below);
                int rk1 = cnt + c0 + __popcll(m1 & below);
                if (q0 && rk0 < S_) sidx[w][rk0] = ma;
                if (q1 && rk1 < S_) sidx[w][rk1] = mc;
                cnt += c0 + __popcll(m1);
            }
            valid = false;
        }
        int first = sidx[w][0];
        int myi = first;
        if (lane < S_){
            myi = (lane < cnt) ? sidx[w][lane] : first;
            idxb[gi*S_ + lane] = myi;
        }
        // fused BN0 stats: lane = channel
        float bse = base[(size_t)gi*64 + lane];
        #pragma unroll 16
        for (int s = 0; s < S_; ++s){
            int ms = __shfl(myi, s);
            float h = bse + hb[(size_t)ms*64];
            asum += h; asq = fmaf(h, h, asq);
        }
    }
    r1[w][lane] = asum; r2[w][lane] = asq;
    __syncthreads();
    {   // per-XCD partial: copy (blockIdx&7); contention/8, no XCD ping-pong
        float* gp = gstat0p + (size_t)(blockIdx.x & (NCOPY-1))*128;
        if (t < 64){
            atomicAdd(&gp[t], r1[0][t]+r1[1][t]+r1[2][t]+r1[3][t]);
        } else if (t < 128){
            int o = t - 64;
            atomicAdd(&gp[64+o], r2[0][o]+r2[1][o]+r2[2][o]+r2[3][o]);
        }
    }
}

// ================= k_main: fused bn0 + bf16 MFMA layer1 + BN1 stats + sel-max
// (256,3): ~150-reg working set fits 170-VGPR budget; (256,4) caused ~100MB
// of spill stores (R3) with occupancy scratch-capped below the 3-wave bound.
// DO NOT raise to (256,4): combined arch+accum regs > 128 (R3 evidence).
__global__ __launch_bounds__(256,3) void k_main(
        const float* __restrict__ H0r, const float* __restrict__ base,
        const int* __restrict__ idxb, const unsigned short* __restrict__ w1b,
        const float* __restrict__ g0, const float* __restrict__ be0,
        const float* __restrict__ g1,
        const float* __restrict__ gstat0p, float* __restrict__ gstat1p,
        float* __restrict__ selb){
    __shared__ unsigned short w1s[8192];     // 16KB, XOR-swizzled bf16 w1
    __shared__ float bn0s[128];
    __shared__ float baseS[16*64];           // 4KB: base rows of block's points
    __shared__ int   idxS[16*S_];            // 2KB: idx rows of block's points
    __shared__ float sred[4][O1_], qred[4][O1_];
    const int t = threadIdx.x, w = t >> 6, l = t & 63;
    const int lr = l & 15, g = l >> 4;
    const int b = blockIdx.x & 7, chunk = blockIdx.x >> 3;
    const int rowb = b*N_;
    const int p0g = rowb + chunk*16;         // first point of this block
    {   // stage w1 (already swizzled in global) -> LDS, linear copy
        const s16x8* src = (const s16x8*)w1b;
        s16x8* dst = (s16x8*)w1s;
        #pragma unroll
        for (int j = 0; j < 4; ++j) dst[t + 256*j] = src[t + 256*j];
        // stage base rows (16*64 f32) and idx rows (16*32 i32), coalesced, NT
        ((f32x4*)baseS)[t] = __builtin_nontemporal_load(
            (const f32x4*)(base + (size_t)p0g*64) + t);
        ((i32x2*)idxS)[t] = __builtin_nontemporal_load(
            (const i32x2*)(idxb + (size_t)p0g*S_) + t);
    }
    if (t < 64){   // fused bn0: sum the 8 per-XCD partials, then scale/shift
        float s0 = 0.f, s1 = 0.f;
        #pragma unroll
        for (int k = 0; k < NCOPY; ++k){
            s0 += gstat0p[k*128 + t];
            s1 += gstat0p[k*128 + 64 + t];
        }
        float mean = s0 * (1.f/MTOTF);
        float var  = s1 * (1.f/MTOTF) - mean*mean;
        float sc = g0[t] * rsqrtf(var + 1e-5f);
        bn0s[t] = sc; bn0s[64+t] = be0[t] - mean*sc;
    }
    __syncthreads();
    // sign of g1 decides max vs min (min = -max(-x)); packed to 1 register
    unsigned smask = 0u;
    #pragma unroll
    for (int nt = 0; nt < 8; ++nt)
        if (g1[nt*16+lr] < 0.f) smask |= (1u << nt);
    const char* wbp = (const char*)w1s;
    int bo0v = lr*128 + ((g*16) ^ ((lr & 7) << 4));
    int bo1v = bo0v ^ 64;
    float bsum[8] = {0,0,0,0,0,0,0,0};
    float bsqr[8] = {0,0,0,0,0,0,0,0};
    float gaf[32];
    auto ISSUE = [&](int i0_, int i1_){
        const float* h0 = H0r + (size_t)(rowb + i0_)*64 + g*8;
        const float* h1 = H0r + (size_t)(rowb + i1_)*64 + g*8;
        *(float4*)&gaf[0]  = ((const float4*)h0)[0];
        *(float4*)&gaf[4]  = ((const float4*)h0)[1];
        *(float4*)&gaf[8]  = *(const float4*)(h0+32);
        *(float4*)&gaf[12] = *(const float4*)(h0+36);
        *(float4*)&gaf[16] = ((const float4*)h1)[0];
        *(float4*)&gaf[20] = ((const float4*)h1)[1];
        *(float4*)&gaf[24] = *(const float4*)(h1+32);
        *(float4*)&gaf[28] = *(const float4*)(h1+36);
    };
    {
        int ci0 = idxS[(w*4)*S_ + lr];
        int ci1 = idxS[(w*4)*S_ + 16 + lr];
        ISSUE(ci0, ci1);
    }
    #pragma unroll 1
    for (int p = 0; p < 4; ++p){
        // opaque touch: compiler must treat w1 LDS offsets as loop-variant,
        // so the 16 ds_read_b128 of w1 cannot be hoisted (64 VGPRs saved)
        asm volatile("" : "+v"(bo0v), "+v"(bo1v));
        const int cgi = p0g + w*4 + p;
        const float* bls = &baseS[(w*4+p)*64];
        // bn0 scale/shift (LDS broadcast), base folded into shift, per-kt half
        s16x8 Af[2][2];
        #pragma unroll
        for (int kt = 0; kt < 2; ++kt){
            float scv[8], shft[8];
            #pragma unroll
            for (int j = 0; j < 8; ++j){
                float sc = bn0s[kt*32 + g*8 + j];
                float sh = bn0s[64 + kt*32 + g*8 + j];
                scv[j] = sc;
                shft[j] = fmaf(sc, bls[kt*32 + g*8 + j], sh);
            }
            #pragma unroll
            for (int mt = 0; mt < 2; ++mt){
                s16x8 f;
                #pragma unroll
                for (int j = 0; j < 8; ++j){
                    float v = fmaf(scv[j], gaf[mt*16+kt*8+j], shft[j]);
                    v = fmaxf(v, 0.2f*v);
                    f[j] = bfr(v);
                }
                Af[mt][kt] = f;
            }
        }
        if (p < 3){   // prefetch next point's H rows under the MFMA loop
            int ni0 = idxS[(w*4+p+1)*S_ + lr];
            int ni1 = idxS[(w*4+p+1)*S_ + 16 + lr];
            ISSUE(ni0, ni1);
        }
        #pragma unroll
        for (int nt = 0; nt < 8; ++nt){
            s16x8 b0 = *(const s16x8*)(wbp + bo0v + nt*2048);
            s16x8 b1 = *(const s16x8*)(wbp + bo1v + nt*2048);
            f32x4 ac0 = {0.f,0.f,0.f,0.f}, ac1 = {0.f,0.f,0.f,0.f};
            ac0 = __builtin_amdgcn_mfma_f32_16x16x32_bf16(Af[0][0], b0, ac0, 0,0,0);
            ac0 = __builtin_amdgcn_mfma_f32_16x16x32_bf16(Af[0][1], b1, ac0, 0,0,0);
            ac1 = __builtin_amdgcn_mfma_f32_16x16x32_bf16(Af[1][0], b0, ac1, 0,0,0);
            ac1 = __builtin_amdgcn_mfma_f32_16x16x32_bf16(Af[1][1], b1, ac1, 0,0,0);
            float v0=ac0[0],v1=ac0[1],v2=ac0[2],v3=ac0[3];
            float v4=ac1[0],v5=ac1[1],v6=ac1[2],v7=ac1[3];
            bsum[nt] += ((v0+v1)+(v2+v3)) + ((v4+v5)+(v6+v7));
            float q = bsqr[nt];
            q = fmaf(v0,v0,q); q = fmaf(v1,v1,q); q = fmaf(v2,v2,q); q = fmaf(v3,v3,q);
            q = fmaf(v4,v4,q); q = fmaf(v5,v5,q); q = fmaf(v6,v6,q); q = fmaf(v7,v7,q);
            bsqr[nt] = q;
            const unsigned s = ((smask >> nt) & 1u) << 31;
            float x0 = __uint_as_float(__float_as_uint(v0)^s);
            float x1 = __uint_as_float(__float_as_uint(v1)^s);
            float x2 = __uint_as_float(__float_as_uint(v2)^s);
            float x3 = __uint_as_float(__float_as_uint(v3)^s);
            float x4 = __uint_as_float(__float_as_uint(v4)^s);
            float x5 = __uint_as_float(__float_as_uint(v5)^s);
            float x6 = __uint_as_float(__float_as_uint(v6)^s);
            float x7 = __uint_as_float(__float_as_uint(v7)^s);
            float mm = fmaxf(fmaxf(fmaxf(x0,x1), fmaxf(x2,x3)),
                             fmaxf(fmaxf(x4,x5), fmaxf(x6,x7)));
            mm = fmaxf(mm, __shfl_xor(mm, 16));
            mm = fmaxf(mm, __shfl_xor(mm, 32));
            if (l < 16)
                __builtin_nontemporal_store(
                    __uint_as_float(__float_as_uint(mm)^s),
                    &selb[(size_t)cgi*O1_ + nt*16 + lr]);
        }
    }
    // BN1-stat reduction: wave -> block -> per-XCD partial atomics
    #pragma unroll
    for (int nt = 0; nt < 8; ++nt){
        float s = bsum[nt]; s += __shfl_xor(s, 16); s += __shfl_xor(s, 32);
        float q = bsqr[nt]; q += __shfl_xor(q, 16); q += __shfl_xor(q, 32);
        if (l < 16){ sred[w][nt*16 + lr] = s; qred[w][nt*16 + lr] = q; }
    }
    __syncthreads();
    {
        float* gp = gstat1p + (size_t)(blockIdx.x & (NCOPY-1))*256;
        if (t < O1_){
            atomicAdd(&gp[t], sred[0][t]+sred[1][t]+sred[2][t]+sred[3][t]);
        } else {
            int o = t - O1_;
            atomicAdd(&gp[O1_+o], qred[0][o]+qred[1][o]+qred[2][o]+qred[3][o]);
        }
    }
}

// ================= k_out: fused bn1 + lrelu + transpose ====================
__global__ __launch_bounds__(256) void k_out(const float* __restrict__ selb,
        const float* __restrict__ gstat1p, const float* __restrict__ g1,
        const float* __restrict__ be1, float* __restrict__ out){
    __shared__ float bn1s[256];
    __shared__ float tr[O1_][65];
    const int t = threadIdx.x;
    if (t < O1_){   // sum the 8 per-XCD partials, then scale/shift
        float s0 = 0.f, s1 = 0.f;
        #pragma unroll
        for (int k = 0; k < NCOPY; ++k){
            s0 += gstat1p[k*256 + t];
            s1 += gstat1p[k*256 + O1_ + t];
        }
        float mean = s0 * (1.f/MTOTF);
        float var  = s1 * (1.f/MTOTF) - mean*mean;
        float sc = g1[t] * rsqrtf(var + 1e-5f);
        bn1s[t] = sc; bn1s[O1_+t] = be1[t] - mean*sc;
    }
    __syncthreads();
    const int b  = blockIdx.x >> 5;
    const int n0 = (blockIdx.x & 31) * 64;
    #pragma unroll
    for (int it = 0; it < 32; ++it){
        int e = t + 256*it;
        int O = e & 127, nl = e >> 7;
        float v = selb[(size_t)(b*N_ + n0 + nl)*O1_ + O];
        tr[O][nl] = lrelu(bn1s[O]*v + bn1s[O1_+O]);
    }
    __syncthreads();
    #pragma unroll
    for (int it = 0; it < 32; ++it){
        int e = t + 256*it;
        int nl = e & 63, O = e >> 6;
        out[((size_t)(b*O1_) + O)*N_ + n0 + nl] = tr[O][nl];
    }
}

extern "C" void kernel_launch(void* const* d_in, const int* in_sizes, int n_in,
                              void* d_out, int out_size, void* d_ws, size_t ws_size,
                              hipStream_t stream){
    const float* pf  = (const float*)d_in[1];
    const float* w0  = (const float*)d_in[2];
    const float* g0  = (const float*)d_in[4];
    const float* be0 = (const float*)d_in[5];
    const float* w1  = (const float*)d_in[6];
    const float* g1  = (const float*)d_in[8];
    const float* be1 = (const float*)d_in[9];
    float* out = (float*)d_out;

    char* ws = (char*)d_ws;
    size_t off = 0;
    auto carve = [&](size_t bytes)->void*{
        void* p = ws + off; off += (bytes + 255) & ~(size_t)255; return p;
    };
    double* ssum  = (double*)carve((size_t)NP_*8);
    int*    idxb  = (int*)   carve((size_t)NP_*S_*4);
    float*  H0r   = (float*) carve((size_t)NP_*64*4);
    float*  base  = (float*) carve((size_t)NP_*64*4);
    float*  pt    = (float*) carve((size_t)NP_*32*4);
    unsigned short* w1b = (unsigned short*)carve(8192*2);
    float*  gstats = (float*)carve((size_t)NCOPY*384*4);  // 8x128 + 8x256
    float*  selb  = (float*) carve((size_t)NP_*O1_*4);
    float* gstat0p = gstats;                 // 8 copies x 128 floats
    float* gstat1p = gstats + NCOPY*128;     // 8 copies x 256 floats

    // no hipMemsetAsync: k_pre block 0 zeroes gstats (fill dispatch was 43us)
    k_pre <<<1024, 256, 0, stream>>>(pf, w0, w1, H0r, base, pt, ssum, w1b,
                                     gstats);
    k_knn <<<1024, 256, 0, stream>>>(pt, ssum, H0r, base, idxb, gstat0p);
    k_main<<<1024, 256, 0, stream>>>(H0r, base, idxb, w1b, g0, be0, g1,
                                     gstat0p, gstat1p, selb);
    k_out <<<256, 256, 0, stream>>>(selb, gstat1p, g1, be1, out);
}

// Round 17
// 88.847 us; speedup vs baseline: 1.1477x; 1.0039x over previous
//
#include <hip/hip_runtime.h>
#include <hip/hip_bf16.h>

#define B_ 8
#define N_ 2048
#define C_ 32
#define S_ 32
#define O1_ 128
#define NP_ (B_*N_)          // 16384 points
#define MTOTF 524288.0f      // B*N*S samples per BN channel
#define NCOPY 8              // stat partial copies (R13 proven; R14's 64 = null)

typedef __attribute__((ext_vector_type(8))) short s16x8;
typedef __attribute__((ext_vector_type(4))) float f32x4;
typedef __attribute__((ext_vector_type(2))) int   i32x2;

__device__ __forceinline__ short bfr(float x){
    return __builtin_bit_cast(short, __float2bfloat16(x));
}
__device__ __forceinline__ float lrelu(float x){ return fmaxf(x, 0.2f*x); }

// ================= k_pre: ssum + point transpose + w0 tables + w1->bf16 ====
// H0r[gi,o] = sum_c w0[o,32+c]*x[c] ; base[gi,o] = sum_c (w0[o,c]-w0[o,32+c])*x[c]
// Batch-pinned mapping (R15) = k_knn/k_main mapping (produce on consuming
// XCD). Block 0 zeroes gstats (R16: replaced the hipMemsetAsync dispatch).
__global__ __launch_bounds__(256) void k_pre(const float* __restrict__ pf,
        const float* __restrict__ w0, const float* __restrict__ w1,
        float* __restrict__ H0r, float* __restrict__ base,
        float* __restrict__ pt, double* __restrict__ ssum,
        unsigned short* __restrict__ w1b, float* __restrict__ gstats){
    __shared__ float w0t[32*65], w0d[32*65];   // transposed, pitch 65
    const int t = threadIdx.x, w = t >> 6, l = t & 63;
    for (int i = t; i < 2048; i += 256){
        int o = i >> 5, c = i & 31;
        float a = w0[o*64 + c], bq = w0[o*64 + 32 + c];
        w0t[c*65 + o] = bq;
        w0d[c*65 + o] = a - bq;
    }
    if (blockIdx.x == 0){
        // w1 -> bf16, XOR-swizzled in global so k_main can linear-copy to LDS
        for (int i = t; i < 8192; i += 256){
            int o = i >> 6, k = i & 63;
            w1b[(o << 6) | (k ^ ((o & 7) << 3))] = (unsigned short)bfr(w1[i]);
        }
        // zero the stat partials (replaces hipMemsetAsync fill dispatch)
        #pragma unroll
        for (int i = 0; i < 3; ++i)
            ((f32x4*)gstats)[t + 256*i] = (f32x4){0.f,0.f,0.f,0.f};
    }
    __syncthreads();
    const int b = blockIdx.x & 7, chunk = blockIdx.x >> 3;   // 128 chunks/batch
    const int gp0 = b*N_ + chunk*16 + w*4;                   // 4 points per wave
    const float* pfb = pf + (size_t)b*C_*N_;
    #pragma unroll 1
    for (int pp = 0; pp < 4; ++pp){
        const int gi = gp0 + pp;
        const int n = gi & (N_-1);
        const float* ppx = pfb + n;
        float hacc = 0.f, dacc = 0.f, xv = 0.f;
        double s = 0.0;
        #pragma unroll
        for (int c = 0; c < 32; ++c){
            float xc = ppx[(size_t)c*N_];         // wave-uniform broadcast load
            hacc = fmaf(w0t[c*65 + l], xc, hacc);
            dacc = fmaf(w0d[c*65 + l], xc, dacc);
            double xd = (double)xc;
            s = fma(xd, xd, s);
            if (l == c) xv = xc;
        }
        H0r[(size_t)gi*64 + l]  = hacc;
        base[(size_t)gi*64 + l] = dacc;
        if (l < 32) pt[(size_t)gi*32 + l] = xv;
        if (l == 0) ssum[gi] = s;
    }
}

// ================= k_knn: ball query (f32) + fused BN0 stats ===============
// batch-pinned: blockIdx&7 = batch -> per-XCD L2 holds one batch's tables
// R17: pair the head passes. The 4 points/wave were fully serial; each head
// = cn-load (~200cy) + 32-deep FMA chain. Points are independent -> compute
// 2 points per head pass with 4 interleaved FMA chains (per-chain accum
// order unchanged = bit-identical). Ballot/tail/gather stay sequential per
// point. Targets the last un-probed serial structure after math/regs/occ/
// atomics/locality were all exonerated (R9..R16).
__global__ __launch_bounds__(256,2) void k_knn(const float* __restrict__ pt,
        const double* __restrict__ ssum, const float* __restrict__ H0r,
        const float* __restrict__ base, int* __restrict__ idxb,
        float* __restrict__ gstat0p){
    __shared__ int sidx[4][S_];
    __shared__ float r1[4][64], r2[4][64];
    const int t = threadIdx.x, w = t >> 6, lane = t & 63;
    const int b = blockIdx.x & 7, chunk = blockIdx.x >> 3;   // 128 chunks/batch
    const int gp0 = b*N_ + chunk*16 + w*4;                   // 4 points per wave
    const float* ptb = pt + (size_t)(b*N_)*32;
    const double* ssb = ssum + (size_t)b*N_;
    const float* hb = H0r + (size_t)(b*N_)*64 + lane;
    const unsigned long long below = (1ull << lane) - 1ull;
    const float4* r0p = (const float4*)(ptb + (size_t)lane*32);
    const float4* r1p = (const float4*)(ptb + (size_t)(64+lane)*32);
    float4 va[8], vb[8];
    #pragma unroll
    for (int j = 0; j < 8; ++j) va[j] = r0p[j];
    #pragma unroll
    for (int j = 0; j < 8; ++j) vb[j] = r1p[j];
    bool valid = true;
    const float ss0 = (float)ssb[lane], ss1 = (float)ssb[64+lane];
    float asum = 0.f, asq = 0.f;
    // per-point finish: ballot -> sidx -> (rare tail) -> idx write -> stats
    auto PROC = [&](int gi, float d0, float d1, float sn, const float* cnp){
        int cnt;
        {
            float sq0 = sn + ss0 - 2.0f*d0;
            float sq1 = sn + ss1 - 2.0f*d1;
            bool q0 = !(sq0 > 64.0f), q1 = !(sq1 > 64.0f);
            unsigned long long m0 = __ballot(q0), m1 = __ballot(q1);
            int p0 = __popcll(m0);
            int rk0 = __popcll(m0 & below);
            int rk1 = p0 + __popcll(m1 & below);
            if (q0 && rk0 < S_) sidx[w][rk0] = lane;
            if (q1 && rk1 < S_) sidx[w][rk1] = 64 + lane;
            cnt = p0 + __popcll(m1);
        }
        if (cnt < S_){   // rare tail: 2 tiles per iteration, clobbers va/vb
            #pragma unroll 1
            for (int mb = 128; mb < N_ && cnt < S_; mb += 128){
                const int ma = mb + lane, mc = mb + 64 + lane;
                const float4* ta = (const float4*)(ptb + (size_t)ma*32);
                const float4* tb = (const float4*)(ptb + (size_t)mc*32);
                #pragma unroll
                for (int j = 0; j < 8; ++j) va[j] = ta[j];
                #pragma unroll
                for (int j = 0; j < 8; ++j) vb[j] = tb[j];
                float d0t = 0.f, d1t = 0.f;
                #pragma unroll
                for (int j = 0; j < 8; ++j){
                    d0t = fmaf(va[j].x, cnp[4*j],   d0t);
                    d0t = fmaf(va[j].y, cnp[4*j+1], d0t);
                    d0t = fmaf(va[j].z, cnp[4*j+2], d0t);
                    d0t = fmaf(va[j].w, cnp[4*j+3], d0t);
                    d1t = fmaf(vb[j].x, cnp[4*j],   d1t);
                    d1t = fmaf(vb[j].y, cnp[4*j+1], d1t);
                    d1t = fmaf(vb[j].z, cnp[4*j+2], d1t);
                    d1t = fmaf(vb[j].w, cnp[4*j+3], d1t);
                }
                float sq0 = sn + (float)ssb[ma] - 2.0f*d0t;
                float sq1 = sn + (float)ssb[mc] - 2.0f*d1t;
                bool q0 = !(sq0 > 64.0f), q1 = !(sq1 > 64.0f);
                unsigned long long m0 = __ballot(q0), m1 = __ballot(q1);
                int c0 = __popcll(m0);
                int rk0 = cnt + __popcll(m0 & below);
                int rk1 = cnt + c0 + __popcll(m1 & below);
                if (q0 && rk0 < S_) sidx[w][rk0] = ma;
                if (q1 && rk1 < S_) sidx[w][rk1] = mc;
                cnt += c0 + __popcll(m1);
            }
            valid = false;
        }
        int first = sidx[w][0];
        int myi = first;
        if (lane < S_){
            myi = (lane < cnt) ? sidx[w][lane] : first;
            idxb[gi*S_ + lane] = myi;
        }
        // fused BN0 stats: lane = channel
        float bse = base[(size_t)gi*64 + lane];
        #pragma unroll 16
        for (int s = 0; s < S_; ++s){
            int ms = __shfl(myi, s);
            float h = bse + hb[(size_t)ms*64];
            asum += h; asq = fmaf(h, h, asq);
        }
    };
    #pragma unroll 1
    for (int pp = 0; pp < 4; pp += 2){
        const int giA = gp0 + pp, giB = gp0 + pp + 1;
        if (!valid){   // a previous tail run clobbered va/vb
            #pragma unroll
            for (int j = 0; j < 8; ++j) va[j] = r0p[j];
            #pragma unroll
            for (int j = 0; j < 8; ++j) vb[j] = r1p[j];
            valid = true;
        }
        float cnA[32], cnB[32];
        {
            const float4* cpA = (const float4*)(pt + (size_t)giA*32);
            const float4* cpB = (const float4*)(pt + (size_t)giB*32);
            #pragma unroll
            for (int j = 0; j < 8; ++j){
                float4 u = cpA[j], v = cpB[j];
                cnA[4*j] = u.x; cnA[4*j+1] = u.y; cnA[4*j+2] = u.z; cnA[4*j+3] = u.w;
                cnB[4*j] = v.x; cnB[4*j+1] = v.y; cnB[4*j+2] = v.z; cnB[4*j+3] = v.w;
            }
        }
        const float snA = (float)ssum[giA], snB = (float)ssum[giB];
        // paired head pass: 4 independent FMA chains (per-chain order = R9)
        float d0a = 0.f, d1a = 0.f, d0b = 0.f, d1b = 0.f;
        #pragma unroll
        for (int j = 0; j < 8; ++j){
            d0a = fmaf(va[j].x, cnA[4*j],   d0a);
            d0b = fmaf(va[j].x, cnB[4*j],   d0b);
            d1a = fmaf(vb[j].x, cnA[4*j],   d1a);
            d1b = fmaf(vb[j].x, cnB[4*j],   d1b);
            d0a = fmaf(va[j].y, cnA[4*j+1], d0a);
            d0b = fmaf(va[j].y, cnB[4*j+1], d0b);
            d1a = fmaf(vb[j].y, cnA[4*j+1], d1a);
            d1b = fmaf(vb[j].y, cnB[4*j+1], d1b);
            d0a = fmaf(va[j].z, cnA[4*j+2], d0a);
            d0b = fmaf(va[j].z, cnB[4*j+2], d0b);
            d1a = fmaf(vb[j].z, cnA[4*j+2], d1a);
            d1b = fmaf(vb[j].z, cnB[4*j+2], d1b);
            d0a = fmaf(va[j].w, cnA[4*j+3], d0a);
            d0b = fmaf(va[j].w, cnB[4*j+3], d0b);
            d1a = fmaf(vb[j].w, cnA[4*j+3], d1a);
            d1b = fmaf(vb[j].w, cnB[4*j+3], d1b);
        }
        PROC(giA, d0a, d1a, snA, cnA);
        PROC(giB, d0b, d1b, snB, cnB);
    }
    r1[w][lane] = asum; r2[w][lane] = asq;
    __syncthreads();
    {   // per-XCD partial: copy (blockIdx&7); contention/8, no XCD ping-pong
        float* gp = gstat0p + (size_t)(blockIdx.x & (NCOPY-1))*128;
        if (t < 64){
            atomicAdd(&gp[t], r1[0][t]+r1[1][t]+r1[2][t]+r1[3][t]);
        } else if (t < 128){
            int o = t - 64;
            atomicAdd(&gp[64+o], r2[0][o]+r2[1][o]+r2[2][o]+r2[3][o]);
        }
    }
}

// ================= k_main: fused bn0 + bf16 MFMA layer1 + BN1 stats + sel-max
// (256,3): ~150-reg working set fits 170-VGPR budget; (256,4) caused ~100MB
// of spill stores (R3) with occupancy scratch-capped below the 3-wave bound.
// DO NOT raise to (256,4): combined arch+accum regs > 128 (R3 evidence).
__global__ __launch_bounds__(256,3) void k_main(
        const float* __restrict__ H0r, const float* __restrict__ base,
        const int* __restrict__ idxb, const unsigned short* __restrict__ w1b,
        const float* __restrict__ g0, const float* __restrict__ be0,
        const float* __restrict__ g1,
        const float* __restrict__ gstat0p, float* __restrict__ gstat1p,
        float* __restrict__ selb){
    __shared__ unsigned short w1s[8192];     // 16KB, XOR-swizzled bf16 w1
    __shared__ float bn0s[128];
    __shared__ float baseS[16*64];           // 4KB: base rows of block's points
    __shared__ int   idxS[16*S_];            // 2KB: idx rows of block's points
    __shared__ float sred[4][O1_], qred[4][O1_];
    const int t = threadIdx.x, w = t >> 6, l = t & 63;
    const int lr = l & 15, g = l >> 4;
    const int b = blockIdx.x & 7, chunk = blockIdx.x >> 3;
    const int rowb = b*N_;
    const int p0g = rowb + chunk*16;         // first point of this block
    {   // stage w1 (already swizzled in global) -> LDS, linear copy
        const s16x8* src = (const s16x8*)w1b;
        s16x8* dst = (s16x8*)w1s;
        #pragma unroll
        for (int j = 0; j < 4; ++j) dst[t + 256*j] = src[t + 256*j];
        // stage base rows (16*64 f32) and idx rows (16*32 i32), coalesced, NT
        ((f32x4*)baseS)[t] = __builtin_nontemporal_load(
            (const f32x4*)(base + (size_t)p0g*64) + t);
        ((i32x2*)idxS)[t] = __builtin_nontemporal_load(
            (const i32x2*)(idxb + (size_t)p0g*S_) + t);
    }
    if (t < 64){   // fused bn0: sum the 8 per-XCD partials, then scale/shift
        float s0 = 0.f, s1 = 0.f;
        #pragma unroll
        for (int k = 0; k < NCOPY; ++k){
            s0 += gstat0p[k*128 + t];
            s1 += gstat0p[k*128 + 64 + t];
        }
        float mean = s0 * (1.f/MTOTF);
        float var  = s1 * (1.f/MTOTF) - mean*mean;
        float sc = g0[t] * rsqrtf(var + 1e-5f);
        bn0s[t] = sc; bn0s[64+t] = be0[t] - mean*sc;
    }
    __syncthreads();
    // sign of g1 decides max vs min (min = -max(-x)); packed to 1 register
    unsigned smask = 0u;
    #pragma unroll
    for (int nt = 0; nt < 8; ++nt)
        if (g1[nt*16+lr] < 0.f) smask |= (1u << nt);
    const char* wbp = (const char*)w1s;
    int bo0v = lr*128 + ((g*16) ^ ((lr & 7) << 4));
    int bo1v = bo0v ^ 64;
    float bsum[8] = {0,0,0,0,0,0,0,0};
    float bsqr[8] = {0,0,0,0,0,0,0,0};
    float gaf[32];
    auto ISSUE = [&](int i0_, int i1_){
        const float* h0 = H0r + (size_t)(rowb + i0_)*64 + g*8;
        const float* h1 = H0r + (size_t)(rowb + i1_)*64 + g*8;
        *(float4*)&gaf[0]  = ((const float4*)h0)[0];
        *(float4*)&gaf[4]  = ((const float4*)h0)[1];
        *(float4*)&gaf[8]  = *(const float4*)(h0+32);
        *(float4*)&gaf[12] = *(const float4*)(h0+36);
        *(float4*)&gaf[16] = ((const float4*)h1)[0];
        *(float4*)&gaf[20] = ((const float4*)h1)[1];
        *(float4*)&gaf[24] = *(const float4*)(h1+32);
        *(float4*)&gaf[28] = *(const float4*)(h1+36);
    };
    {
        int ci0 = idxS[(w*4)*S_ + lr];
        int ci1 = idxS[(w*4)*S_ + 16 + lr];
        ISSUE(ci0, ci1);
    }
    #pragma unroll 1
    for (int p = 0; p < 4; ++p){
        // opaque touch: compiler must treat w1 LDS offsets as loop-variant,
        // so the 16 ds_read_b128 of w1 cannot be hoisted (64 VGPRs saved)
        asm volatile("" : "+v"(bo0v), "+v"(bo1v));
        const int cgi = p0g + w*4 + p;
        const float* bls = &baseS[(w*4+p)*64];
        // bn0 scale/shift (LDS broadcast), base folded into shift, per-kt half
        s16x8 Af[2][2];
        #pragma unroll
        for (int kt = 0; kt < 2; ++kt){
            float scv[8], shft[8];
            #pragma unroll
            for (int j = 0; j < 8; ++j){
                float sc = bn0s[kt*32 + g*8 + j];
                float sh = bn0s[64 + kt*32 + g*8 + j];
                scv[j] = sc;
                shft[j] = fmaf(sc, bls[kt*32 + g*8 + j], sh);
            }
            #pragma unroll
            for (int mt = 0; mt < 2; ++mt){
                s16x8 f;
                #pragma unroll
                for (int j = 0; j < 8; ++j){
                    float v = fmaf(scv[j], gaf[mt*16+kt*8+j], shft[j]);
                    v = fmaxf(v, 0.2f*v);
                    f[j] = bfr(v);
                }
                Af[mt][kt] = f;
            }
        }
        if (p < 3){   // prefetch next point's H rows under the MFMA loop
            int ni0 = idxS[(w*4+p+1)*S_ + lr];
            int ni1 = idxS[(w*4+p+1)*S_ + 16 + lr];
            ISSUE(ni0, ni1);
        }
        #pragma unroll
        for (int nt = 0; nt < 8; ++nt){
            s16x8 b0 = *(const s16x8*)(wbp + bo0v + nt*2048);
            s16x8 b1 = *(const s16x8*)(wbp + bo1v + nt*2048);
            f32x4 ac0 = {0.f,0.f,0.f,0.f}, ac1 = {0.f,0.f,0.f,0.f};
            ac0 = __builtin_amdgcn_mfma_f32_16x16x32_bf16(Af[0][0], b0, ac0, 0,0,0);
            ac0 = __builtin_amdgcn_mfma_f32_16x16x32_bf16(Af[0][1], b1, ac0, 0,0,0);
            ac1 = __builtin_amdgcn_mfma_f32_16x16x32_bf16(Af[1][0], b0, ac1, 0,0,0);
            ac1 = __builtin_amdgcn_mfma_f32_16x16x32_bf16(Af[1][1], b1, ac1, 0,0,0);
            float v0=ac0[0],v1=ac0[1],v2=ac0[2],v3=ac0[3];
            float v4=ac1[0],v5=ac1[1],v6=ac1[2],v7=ac1[3];
            bsum[nt] += ((v0+v1)+(v2+v3)) + ((v4+v5)+(v6+v7));
            float q = bsqr[nt];
            q = fmaf(v0,v0,q); q = fmaf(v1,v1,q); q = fmaf(v2,v2,q); q = fmaf(v3,v3,q);
            q = fmaf(v4,v4,q); q = fmaf(v5,v5,q); q = fmaf(v6,v6,q); q = fmaf(v7,v7,q);
            bsqr[nt] = q;
            const unsigned s = ((smask >> nt) & 1u) << 31;
            float x0 = __uint_as_float(__float_as_uint(v0)^s);
            float x1 = __uint_as_float(__float_as_uint(v1)^s);
            float x2 = __uint_as_float(__float_as_uint(v2)^s);
            float x3 = __uint_as_float(__float_as_uint(v3)^s);
            float x4 = __uint_as_float(__float_as_uint(v4)^s);
            float x5 = __uint_as_float(__float_as_uint(v5)^s);
            float x6 = __uint_as_float(__float_as_uint(v6)^s);
            float x7 = __uint_as_float(__float_as_uint(v7)^s);
            float mm = fmaxf(fmaxf(fmaxf(x0,x1), fmaxf(x2,x3)),
                             fmaxf(fmaxf(x4,x5), fmaxf(x6,x7)));
            mm = fmaxf(mm, __shfl_xor(mm, 16));
            mm = fmaxf(mm, __shfl_xor(mm, 32));
            if (l < 16)
                __builtin_nontemporal_store(
                    __uint_as_float(__float_as_uint(mm)^s),
                    &selb[(size_t)cgi*O1_ + nt*16 + lr]);
        }
    }
    // BN1-stat reduction: wave -> block -> per-XCD partial atomics
    #pragma unroll
    for (int nt = 0; nt < 8; ++nt){
        float s = bsum[nt]; s += __shfl_xor(s, 16); s += __shfl_xor(s, 32);
        float q = bsqr[nt]; q += __shfl_xor(q, 16); q += __shfl_xor(q, 32);
        if (l < 16){ sred[w][nt*16 + lr] = s; qred[w][nt*16 + lr] = q; }
    }
    __syncthreads();
    {
        float* gp = gstat1p + (size_t)(blockIdx.x & (NCOPY-1))*256;
        if (t < O1_){
            atomicAdd(&gp[t], sred[0][t]+sred[1][t]+sred[2][t]+sred[3][t]);
        } else {
            int o = t - O1_;
            atomicAdd(&gp[O1_+o], qred[0][o]+qred[1][o]+qred[2][o]+qred[3][o]);
        }
    }
}

// ================= k_out: fused bn1 + lrelu + transpose ====================
__global__ __launch_bounds__(256) void k_out(const float* __restrict__ selb,
        const float* __restrict__ gstat1p, const float* __restrict__ g1,
        const float* __restrict__ be1, float* __restrict__ out){
    __shared__ float bn1s[256];
    __shared__ float tr[O1_][65];
    const int t = threadIdx.x;
    if (t < O1_){   // sum the 8 per-XCD partials, then scale/shift
        float s0 = 0.f, s1 = 0.f;
        #pragma unroll
        for (int k = 0; k < NCOPY; ++k){
            s0 += gstat1p[k*256 + t];
            s1 += gstat1p[k*256 + O1_ + t];
        }
        float mean = s0 * (1.f/MTOTF);
        float var  = s1 * (1.f/MTOTF) - mean*mean;
        float sc = g1[t] * rsqrtf(var + 1e-5f);
        bn1s[t] = sc; bn1s[O1_+t] = be1[t] - mean*sc;
    }
    __syncthreads();
    const int b  = blockIdx.x >> 5;
    const int n0 = (blockIdx.x & 31) * 64;
    #pragma unroll
    for (int it = 0; it < 32; ++it){
        int e = t + 256*it;
        int O = e & 127, nl = e >> 7;
        float v = selb[(size_t)(b*N_ + n0 + nl)*O1_ + O];
        tr[O][nl] = lrelu(bn1s[O]*v + bn1s[O1_+O]);
    }
    __syncthreads();
    #pragma unroll
    for (int it = 0; it < 32; ++it){
        int e = t + 256*it;
        int nl = e & 63, O = e >> 6;
        out[((size_t)(b*O1_) + O)*N_ + n0 + nl] = tr[O][nl];
    }
}

extern "C" void kernel_launch(void* const* d_in, const int* in_sizes, int n_in,
                              void* d_out, int out_size, void* d_ws, size_t ws_size,
                              hipStream_t stream){
    const float* pf  = (const float*)d_in[1];
    const float* w0  = (const float*)d_in[2];
    const float* g0  = (const float*)d_in[4];
    const float* be0 = (const float*)d_in[5];
    const float* w1  = (const float*)d_in[6];
    const float* g1  = (const float*)d_in[8];
    const float* be1 = (const float*)d_in[9];
    float* out = (float*)d_out;

    char* ws = (char*)d_ws;
    size_t off = 0;
    auto carve = [&](size_t bytes)->void*{
        void* p = ws + off; off += (bytes + 255) & ~(size_t)255; return p;
    };
    double* ssum  = (double*)carve((size_t)NP_*8);
    int*    idxb  = (int*)   carve((size_t)NP_*S_*4);
    float*  H0r   = (float*) carve((size_t)NP_*64*4);
    float*  base  = (float*) carve((size_t)NP_*64*4);
    float*  pt    = (float*) carve((size_t)NP_*32*4);
    unsigned short* w1b = (unsigned short*)carve(8192*2);
    float*  gstats = (float*)carve((size_t)NCOPY*384*4);  // 8x128 + 8x256
    float*  selb  = (float*) carve((size_t)NP_*O1_*4);
    float* gstat0p = gstats;                 // 8 copies x 128 floats
    float* gstat1p = gstats + NCOPY*128;     // 8 copies x 256 floats

    // no hipMemsetAsync: k_pre block 0 zeroes gstats (R16: saved ~4.6us)
    k_pre <<<1024, 256, 0, stream>>>(pf, w0, w1, H0r, base, pt, ssum, w1b,
                                     gstats);
    k_knn <<<1024, 256, 0, stream>>>(pt, ssum, H0r, base, idxb, gstat0p);
    k_main<<<1024, 256, 0, stream>>>(H0r, base, idxb, w1b, g0, be0, g1,
                                     gstat0p, gstat1p, selb);
    k_out <<<256, 256, 0, stream>>>(selb, gstat1p, g1, be1, out);
}